// Round 1
// baseline (110.479 us; speedup 1.0000x reference)
//
#include <hip/hip_runtime.h>

// Conv4D: x (2,8,7,7,48,48) fp32, kernel 3x3x3x3 pad 1, 8->8 channels.
// out[b,o,u,v,h,w] = bias[o] + sum_{i0,i1,i2,i3,c} x[b,c,u+i0-1,v+i1-1,h+i2-1,w+i3-1]
//                    * conv[o, ((i0*3+i1)*3+i2)*3+i3)*8 + c]
//
// Strategy: fp32 vector kernel (no fp32 MFMA on CDNA4).
//  - block = 256 threads over contiguous hw (coalesced), (b,u,v) uniform per block
//  - weights staged to LDS transposed [tap*8+c][o] -> wave-uniform broadcast reads
//  - per-thread precomputed byte offsets + float masks for the 3x3 (h,w) taps
//  - scalar (wave-uniform) skip of invalid u/v taps: saves ~18% FLOPs

#define SLICE 2304            // 48*48
#define CSTRIDE (49 * 2304)   // stride between channels (u*v*h*w)

__global__ __launch_bounds__(256, 4)
void conv4d_kernel(const float* __restrict__ x,
                   const float* __restrict__ conv,
                   const float* __restrict__ bias,
                   float* __restrict__ out) {
    __shared__ float wlds[81 * 8 * 8];   // [tap*8 + c][o], 20.7 KB

    // Stage weights transposed: wlds[(tap*8+c)*8 + o] = conv[o*648 + tap*8 + c].
    // Coalesced global read, strided LDS write (tiny, one-time).
    for (int i = threadIdx.x; i < 5184; i += 256) {
        int o = i / 648;
        int k = i - o * 648;
        wlds[k * 8 + o] = conv[i];
    }
    __syncthreads();

    const int img = blockIdx.y;          // b*49 + u*7 + v
    const int b   = img / 49;
    const int uvr = img - b * 49;
    const int u   = uvr / 7;
    const int v   = uvr - u * 7;

    const int hw = blockIdx.x * 256 + threadIdx.x;   // 2304 = 9 * 256
    const int h  = hw / 48;
    const int w  = hw - h * 48;

    // Per-thread 3x3 (i2,i3) spatial tap byte-offsets + 0/1 float masks.
    // Invalid taps clamp to a safe in-slice offset (hw) and get masked to 0;
    // the masked garbage value is a finite float from x, so v*0 == 0 exactly.
    int   boff[9];
    float fmask[9];
#pragma unroll
    for (int i2 = 0; i2 < 3; ++i2) {
#pragma unroll
        for (int i3 = 0; i3 < 3; ++i3) {
            int hh = h + i2 - 1, ww = w + i3 - 1;
            bool ok = ((unsigned)hh < 48u) && ((unsigned)ww < 48u);
            boff[i2 * 3 + i3]  = (ok ? (hh * 48 + ww) : hw) * 4;
            fmask[i2 * 3 + i3] = ok ? 1.0f : 0.0f;
        }
    }

    float acc[8];
#pragma unroll
    for (int o = 0; o < 8; ++o) acc[o] = bias[o];

    for (int i0 = 0; i0 < 3; ++i0) {
        const int uu = u + i0 - 1;
        if ((unsigned)uu >= 7u) continue;            // wave-uniform skip
        for (int i1 = 0; i1 < 3; ++i1) {
            const int vv = v + i1 - 1;
            if ((unsigned)vv >= 7u) continue;        // wave-uniform skip
            const int tapbase = (i0 * 3 + i1) * 9;
            const char* xb = (const char*)(x + (b * 8 * 49 + uu * 7 + vv) * SLICE);
            for (int c = 0; c < 8; ++c) {
                const char* base = xb + (size_t)c * (CSTRIDE * 4);
                float xv[9];
#pragma unroll
                for (int k9 = 0; k9 < 9; ++k9)
                    xv[k9] = *(const float*)(base + boff[k9]) * fmask[k9];
#pragma unroll
                for (int k9 = 0; k9 < 9; ++k9) {
                    const float4* wr =
                        (const float4*)&wlds[((tapbase + k9) * 8 + c) * 8];
                    float4 w0 = wr[0];
                    float4 w1 = wr[1];
                    acc[0] = fmaf(xv[k9], w0.x, acc[0]);
                    acc[1] = fmaf(xv[k9], w0.y, acc[1]);
                    acc[2] = fmaf(xv[k9], w0.z, acc[2]);
                    acc[3] = fmaf(xv[k9], w0.w, acc[3]);
                    acc[4] = fmaf(xv[k9], w1.x, acc[4]);
                    acc[5] = fmaf(xv[k9], w1.y, acc[5]);
                    acc[6] = fmaf(xv[k9], w1.z, acc[6]);
                    acc[7] = fmaf(xv[k9], w1.w, acc[7]);
                }
            }
        }
    }

    float* ob = out + (size_t)(b * 8 * 49 + uvr) * SLICE + hw;
#pragma unroll
    for (int o = 0; o < 8; ++o)
        ob[(size_t)o * CSTRIDE] = acc[o];
}

extern "C" void kernel_launch(void* const* d_in, const int* in_sizes, int n_in,
                              void* d_out, int out_size, void* d_ws, size_t ws_size,
                              hipStream_t stream) {
    const float* x    = (const float*)d_in[0];
    const float* conv = (const float*)d_in[1];
    const float* bias = (const float*)d_in[2];
    float* out = (float*)d_out;

    dim3 grid(9, 98);   // 9 hw-tiles of 256, 98 = 2*7*7 (b,u,v) images
    conv4d_kernel<<<grid, dim3(256), 0, stream>>>(x, conv, bias, out);
}

// Round 2
// 80.647 us; speedup vs baseline: 1.3699x; 1.3699x over previous
//
#include <hip/hip_runtime.h>

// Conv4D (2,8,7,7,48,48) fp32, 3x3x3x3 pad 1, 8->8 ch — bf16 MFMA implicit GEMM.
//
// out[b,o,uv,s] = bias[o] + sum_{tap,c} W[o,tap,c] * x[b,c,uv+Duv(tap), s+Dhw(tap)]
//
// Formulated per 16-spatial tile as M=16(o, 8 used) x N=16(spatial) x K=648 GEMM:
// 21 chunks of v_mfma_f32_16x16x32_bf16, K-chunk = 4 taps x 8 channels
// (taps padded 81->84 with zero weights).
//
// d_ws layout (needs ~3.99 MB; re-poisoned each launch -> fully rewritten):
//   [0,        3920000)  xp: bf16 x, layout [b][u][v][hh 50][ww 50][c 8], h/w halo zeros
//   [3920000,  3960000)  zero slice (50*50*8 bf16) for out-of-range (u,v) taps
//   [3960000,  3981504)  Wp: weights in A-fragment order [chunk 21][lane 64][j 8] bf16

typedef __attribute__((ext_vector_type(8))) short short8;
typedef __attribute__((ext_vector_type(4))) float f32x4;

#define CSTRIDE (49 * 2304)
#define XP_BYTES 3920000
#define ZS_OFF   3920000
#define WP_OFF   3960000

__device__ __forceinline__ unsigned short f2bf(float f) {
    union { float f; unsigned u; } v; v.f = f;
    unsigned u = v.u;
    return (unsigned short)((u + 0x7FFF + ((u >> 16) & 1)) >> 16);  // RNE
}

// Build xp (245000 groups of 8 ch) + zero slice (2500 groups). 247500 groups total.
__global__ __launch_bounds__(256)
void prep_x(const float* __restrict__ x, unsigned short* __restrict__ ws16) {
    int g = blockIdx.x * 256 + threadIdx.x;
    if (g >= 247500) return;
    unsigned short vals[8];
#pragma unroll
    for (int c = 0; c < 8; ++c) vals[c] = 0;
    if (g < 245000) {
        int b  = g / 122500;          // 49*2500
        int r  = g - b * 122500;
        int uv = r / 2500;
        int p  = r - uv * 2500;
        int hh = p / 50, ww = p - hh * 50;
        int h = hh - 1, w = ww - 1;
        if (((unsigned)h < 48u) && ((unsigned)w < 48u)) {
            const float* xb = x + ((size_t)b * 8 * 49 + uv) * 2304 + h * 48 + w;
#pragma unroll
            for (int c = 0; c < 8; ++c) vals[c] = f2bf(xb[(size_t)c * CSTRIDE]);
        }
    }
    *(short8*)(ws16 + (size_t)g * 8) = *(const short8*)vals;
}

// Weights into A-fragment order: Wp[chunk][lane][j] = W[o=lane&15][tap=chunk*4+(lane>>4)][c=j]
__global__ __launch_bounds__(256)
void prep_w(const float* __restrict__ conv, unsigned short* __restrict__ wp) {
    int i = blockIdx.x * 256 + threadIdx.x;
    if (i >= 10752) return;                  // 21*64*8
    int chunk = i >> 9;
    int rem   = i & 511;
    int lane  = rem >> 3, j = rem & 7;
    int m = lane & 15, q = lane >> 4;
    int tap = chunk * 4 + q;
    unsigned short v = 0;
    if (m < 8 && tap < 81) v = f2bf(conv[m * 648 + tap * 8 + j]);
    wp[i] = v;
}

__global__ __launch_bounds__(256, 4)
void conv4d_mfma(const unsigned short* __restrict__ ws16,
                 const float* __restrict__ bias,
                 float* __restrict__ out) {
    __shared__ int taboff[84];

    const int img = blockIdx.y;              // b*49 + uv
    const int b   = img / 49;
    const int uvr = img - b * 49;
    const int u   = uvr / 7;
    const int v   = uvr - u * 7;

    if (threadIdx.x < 84) {
        int tap = threadIdx.x;
        int i0 = tap / 27, r = tap - i0 * 27;
        int i1 = r / 9;    r -= i1 * 9;
        int i2 = r / 3,    i3 = r - i2 * 3;
        int uu = u + i0 - 1, vv = v + i1 - 1;
        bool valid = (tap < 81) && ((unsigned)uu < 7u) && ((unsigned)vv < 7u);
        int so = valid ? (((b * 7 + uu) * 7 + vv) * 2500) * 16 : ZS_OFF;
        taboff[tap] = so + (i2 * 50 + i3) * 16;
    }
    __syncthreads();

    const int lane = threadIdx.x & 63;
    const int wave = threadIdx.x >> 6;
    const int n    = lane & 15;              // spatial within tile (B cols)
    const int quad = lane >> 4;
    const int sbase = blockIdx.x * 256 + wave * 64;

    int myoff[4];
#pragma unroll
    for (int t = 0; t < 4; ++t) {
        int s = sbase + t * 16 + n;
        int h = s / 48, w = s - h * 48;      // 16 | 48: no row crossing in a quad-group
        myoff[t] = (h * 50 + w) * 16;
    }

    const char* xpb = (const char*)ws16;
    const char* wpb = xpb + WP_OFF;

    f32x4 acc[4];
#pragma unroll
    for (int t = 0; t < 4; ++t) acc[t] = (f32x4){0.f, 0.f, 0.f, 0.f};

    for (int chunk = 0; chunk < 21; ++chunk) {
        short8 wf = *(const short8*)(wpb + chunk * 1024 + lane * 16);
        int toff  = taboff[chunk * 4 + quad];
        const char* base = xpb + toff;
#pragma unroll
        for (int t = 0; t < 4; ++t) {
            short8 xf = *(const short8*)(base + myoff[t]);
            acc[t] = __builtin_amdgcn_mfma_f32_16x16x32_bf16(wf, xf, acc[t], 0, 0, 0);
        }
    }

    // C/D layout: row(=o) = quad*4 + reg, col(=spatial) = lane&15. Rows 8..15 unused.
    if (quad < 2) {
        f32x4 bb = *(const f32x4*)(bias + quad * 4);
        float* ob = out + ((size_t)b * 8 * 49 + uvr) * 2304;
#pragma unroll
        for (int t = 0; t < 4; ++t) {
            int s = sbase + t * 16 + n;
#pragma unroll
            for (int r = 0; r < 4; ++r) {
                int o = quad * 4 + r;
                ob[(size_t)o * CSTRIDE + s] = acc[t][r] + bb[r];
            }
        }
    }
}

extern "C" void kernel_launch(void* const* d_in, const int* in_sizes, int n_in,
                              void* d_out, int out_size, void* d_ws, size_t ws_size,
                              hipStream_t stream) {
    const float* x    = (const float*)d_in[0];
    const float* conv = (const float*)d_in[1];
    const float* bias = (const float*)d_in[2];
    float* out = (float*)d_out;
    unsigned short* ws16 = (unsigned short*)d_ws;

    prep_x<<<dim3((247500 + 255) / 256), dim3(256), 0, stream>>>(x, ws16);
    prep_w<<<dim3((10752 + 255) / 256), dim3(256), 0, stream>>>(conv, ws16 + WP_OFF / 2);
    conv4d_mfma<<<dim3(9, 98), dim3(256), 0, stream>>>(ws16, bias, out);
}

// Round 3
// 79.437 us; speedup vs baseline: 1.3908x; 1.0152x over previous
//
#include <hip/hip_runtime.h>

// Conv4D (2,8,7,7,48,48) fp32, 3x3x3x3 pad 1, 8->8 ch — bf16 MFMA implicit GEMM.
// R3: fused prep, weights in LDS, per-block valid-(u,v)-tap compaction.
//
// out[b,o,uv,s] = bias[o] + sum_{tap,c} W[o,tap,c] * x[b,c,uv+Duv(tap), s+Dhw(tap)]
// Per 16-spatial tile: M=16(o; 8 used) x N=16 x K=nvalid*72 GEMM via
// v_mfma_f32_16x16x32_bf16; K-chunk = 4 tap-slots x 8 channels.
// Compaction: only (u+i0-1, v+i1-1) in-range uv-taps enter the slot list
// (interior: 21 chunks, edge: 14, corner: 9 — avg 17.2 vs fixed 21).
//
// d_ws layout (re-poisoned to 0xAA each launch; fully rewritten by prep):
//   [0,       3920000)  xp: bf16 x as [b][u][v][hh 50][ww 50][c 8], h/w halo zeros
//   [3920000, 3960000)  zero slice (50*50*8 bf16) backing pad slots
//   [3960000, 3980992)  Wp: A-fragment weights [tap 82][m 16][j 8] bf16 (tap 81 = 0)

typedef __attribute__((ext_vector_type(8))) short short8;
typedef __attribute__((ext_vector_type(4))) float f32x4;
typedef __attribute__((ext_vector_type(4))) int   i32x4;

#define CSTRIDE (49 * 2304)
#define ZS_OFF   3920000
#define WP_OFF   3960000
#define WP_BYTES 20992          // 82 taps * 256 B

__device__ __forceinline__ unsigned short f2bf(float f) {
    union { float f; unsigned u; } v; v.f = f;
    unsigned u = v.u;
    return (unsigned short)((u + 0x7FFF + ((u >> 16) & 1)) >> 16);  // RNE
}

// Fused prep: g < 247500 -> xp groups (245000 real + 2500 zero-slice),
//             else       -> Wp element (10496 = 82*128).
__global__ __launch_bounds__(256)
void prep(const float* __restrict__ x, const float* __restrict__ conv,
          unsigned short* __restrict__ ws16) {
    int g = blockIdx.x * 256 + threadIdx.x;
    if (g < 247500) {
        unsigned short vals[8];
#pragma unroll
        for (int c = 0; c < 8; ++c) vals[c] = 0;
        if (g < 245000) {
            int b  = g / 122500;
            int r  = g - b * 122500;
            int uv = r / 2500;
            int p  = r - uv * 2500;
            int hh = p / 50, ww = p - hh * 50;
            int h = hh - 1, w = ww - 1;
            if (((unsigned)h < 48u) && ((unsigned)w < 48u)) {
                const float* xb = x + ((size_t)b * 8 * 49 + uv) * 2304 + h * 48 + w;
#pragma unroll
                for (int c = 0; c < 8; ++c) vals[c] = f2bf(xb[(size_t)c * CSTRIDE]);
            }
        }
        *(short8*)(ws16 + (size_t)g * 8) = *(const short8*)vals;
    } else {
        int i = g - 247500;
        if (i < 10496) {                      // Wp[tap][m][j]
            int tap = i >> 7;
            int r   = i & 127;
            int m   = r >> 3, j = r & 7;
            unsigned short v = 0;
            if (tap < 81 && m < 8) v = f2bf(conv[m * 648 + tap * 8 + j]);
            ws16[WP_OFF / 2 + i] = v;
        }
    }
}

__global__ __launch_bounds__(256, 4)
void conv4d_mfma(const unsigned short* __restrict__ ws16,
                 const float* __restrict__ bias,
                 float* __restrict__ out) {
    __shared__ unsigned short wlds[WP_BYTES / 2];  // [tap][m][j], 20992 B
    __shared__ int taboff_s[84];                   // per-slot xp byte offset
    __shared__ int woff_s[84];                     // per-slot wlds byte offset
    __shared__ int s_vt[9];
    __shared__ int s_nv;

    const int img = blockIdx.y;              // b*49 + uv
    const int b   = img / 49;
    const int uvr = img - b * 49;
    const int u   = uvr / 7;
    const int v   = uvr - u * 7;

    // Stage weights global->LDS (1312 x 16 B, coalesced).
    {
        const i32x4* wsrc = (const i32x4*)((const char*)ws16 + WP_OFF);
        i32x4* wdst = (i32x4*)wlds;
        for (int i = threadIdx.x; i < WP_BYTES / 16; i += 256) wdst[i] = wsrc[i];
    }

    // Valid (i0,i1) list (wave-uniform work, trivial).
    if (threadIdx.x == 0) {
        int nv = 0;
        for (int i01 = 0; i01 < 9; ++i01) {
            int i0 = i01 / 3, i1 = i01 - 3 * i0;
            int uu = u + i0 - 1, vv = v + i1 - 1;
            if (((unsigned)uu < 7u) && ((unsigned)vv < 7u)) s_vt[nv++] = i01;
        }
        s_nv = nv;
    }
    __syncthreads();

    const int nv     = s_nv;
    const int nchunk = (nv * 9 + 3) >> 2;

    // Fill compacted slot tables.
    if (threadIdx.x < 84) {
        int s = threadIdx.x;
        if (s < nv * 9) {
            int g9  = s / 9, hw9 = s - 9 * g9;
            int i01 = s_vt[g9];
            int i0 = i01 / 3, i1 = i01 - 3 * i0;
            int i2 = hw9 / 3, i3 = hw9 - 3 * i2;
            int uu = u + i0 - 1, vv = v + i1 - 1;
            taboff_s[s] = ((((b * 7 + uu) * 7 + vv) * 2500) + i2 * 50 + i3) * 16;
            woff_s[s]   = (i01 * 9 + hw9) * 256;
        } else if (s < 84) {
            taboff_s[s] = ZS_OFF;
            woff_s[s]   = 81 * 256;            // zero weights
        }
    }
    __syncthreads();

    const int lane  = threadIdx.x & 63;
    const int wave  = threadIdx.x >> 6;
    const int n     = lane & 15;               // spatial col within 16-tile
    const int quad  = lane >> 4;               // tap-slot within chunk
    const int sbase = blockIdx.x * 256 + wave * 64;

    int myoff[4];
#pragma unroll
    for (int t = 0; t < 4; ++t) {
        int s = sbase + t * 16 + n;
        int h = s / 48, w = s - h * 48;        // 16 | 48: h uniform per 16-group
        myoff[t] = (h * 50 + w) * 16;
    }

    const char* xpb = (const char*)ws16;
    const char* wld = (const char*)wlds;

    f32x4 acc[4];
#pragma unroll
    for (int t = 0; t < 4; ++t) acc[t] = (f32x4){0.f, 0.f, 0.f, 0.f};

    for (int c = 0; c < nchunk; ++c) {
        int slot = 4 * c + quad;
        int toff = taboff_s[slot];
        int woff = woff_s[slot];
        short8 wf = *(const short8*)(wld + woff + n * 16);
        const char* base = xpb + toff;
#pragma unroll
        for (int t = 0; t < 4; ++t) {
            short8 xf = *(const short8*)(base + myoff[t]);
            acc[t] = __builtin_amdgcn_mfma_f32_16x16x32_bf16(wf, xf, acc[t], 0, 0, 0);
        }
    }

    // C/D: row(=o) = quad*4 + reg, col(=spatial) = lane&15. Rows 8..15 unused.
    if (quad < 2) {
        f32x4 bb = *(const f32x4*)(bias + quad * 4);
        float* ob = out + ((size_t)b * 8 * 49 + uvr) * 2304;
#pragma unroll
        for (int t = 0; t < 4; ++t) {
            int s = sbase + t * 16 + n;
#pragma unroll
            for (int r = 0; r < 4; ++r) {
                int o = quad * 4 + r;
                ob[(size_t)o * CSTRIDE + s] = acc[t][r] + bb[r];
            }
        }
    }
}

extern "C" void kernel_launch(void* const* d_in, const int* in_sizes, int n_in,
                              void* d_out, int out_size, void* d_ws, size_t ws_size,
                              hipStream_t stream) {
    const float* x    = (const float*)d_in[0];
    const float* conv = (const float*)d_in[1];
    const float* bias = (const float*)d_in[2];
    float* out = (float*)d_out;
    unsigned short* ws16 = (unsigned short*)d_ws;

    prep<<<dim3((247500 + 10496 + 255) / 256), dim3(256), 0, stream>>>(x, conv, ws16);
    conv4d_mfma<<<dim3(9, 98), dim3(256), 0, stream>>>(ws16, bias, out);
}